// Round 5
// baseline (57.169 us; speedup 1.0000x reference)
//
#include <hip/hip_runtime.h>
#include <math.h>

#define NN 2048
#define INDIM 256
#define ODIM 64
#define NH 8
#define DHD 8
#define LOG2E 1.44269504088896340736f
#define JSPLIT 4
#define JCHUNK (NN / JSPLIT)   // 512
#define IBLK 4

// K1: wh = h@W^T + b (stored bf16 [j][h][d]); eiL=(ei+ab)*log2e; ejL=ej*log2e.
// grid 512 x 256 thr; 4 nodes/block, one wave per node (lane = out col).
__global__ __launch_bounds__(256) void gat_pre(
    const float* __restrict__ h, const float* __restrict__ Ww,
    const float* __restrict__ Wb, const float* __restrict__ aw,
    const float* __restrict__ ab,
    unsigned short* __restrict__ whb, float* __restrict__ eiL,
    float* __restrict__ ejL)
{
    __shared__ float sH[IBLK][INDIM];        // 4 KB
    const int t = threadIdx.x;
    const int n0 = blockIdx.x * 4;
    ((float4*)&sH[0][0])[t] = ((const float4*)(h + (size_t)n0 * INDIM))[t];
    __syncthreads();

    const int o  = t & 63;
    const int wv = t >> 6;                   // node within block
    const int n  = n0 + wv;
    const float4* w4 = (const float4*)(Ww + (size_t)o * INDIM);
    float acc = 0.f;
#pragma unroll 8
    for (int k = 0; k < INDIM / 4; ++k) {
        const float4 wk = w4[k];
        const float4 hv = *(const float4*)&sH[wv][k * 4];
        acc = fmaf(wk.x, hv.x, acc); acc = fmaf(wk.y, hv.y, acc);
        acc = fmaf(wk.z, hv.z, acc); acc = fmaf(wk.w, hv.w, acc);
    }
    acc += Wb[o];

    // bf16 RNE pack of wh
    {
        unsigned int u = __float_as_uint(acc);
        unsigned int r = (u + 0x7FFF + ((u >> 16) & 1)) >> 16;
        whb[(size_t)n * ODIM + o] = (unsigned short)r;
    }

    const int d = o & 7;
    float pi = acc * aw[d];
    float pj = acc * aw[NH + d];
    pi += __shfl_xor(pi, 1, 64); pj += __shfl_xor(pj, 1, 64);
    pi += __shfl_xor(pi, 2, 64); pj += __shfl_xor(pj, 2, 64);
    pi += __shfl_xor(pi, 4, 64); pj += __shfl_xor(pj, 4, 64);
    if (d == 0) {
        const int hd = o >> 3;
        eiL[n * NH + hd] = (pi + ab[0]) * LOG2E;
        ejL[n * NH + hd] = pj * LOG2E;
    }
}

// K2: block = (i-tile of 4 rows) x (j-chunk of 512). 2048 blocks x 512 thr
// (8 waves). Thread = (jj 0..63, hh 0..7). Writes partial acc/den to ws.
__global__ __launch_bounds__(512, 8) void gat_main(
    const int* __restrict__ adj, const unsigned short* __restrict__ whb,
    const float* __restrict__ eiL, const float* __restrict__ ejL,
    float* __restrict__ pacc, float* __restrict__ pden)
{
    __shared__ unsigned char s_bits[JCHUNK]; // 512 B
    __shared__ float s_red[8][8][IBLK][9];   // 9.2 KB: wave, head, i, d/den
    const int t  = threadIdx.x;
    const int i0 = (blockIdx.x >> 2) * IBLK;
    const int js = blockIdx.x & 3;
    const int jbase = js * JCHUNK;

    {   // bit-pack 4 adjacency rows for this j-chunk
        unsigned int b = 0;
#pragma unroll
        for (int i = 0; i < IBLK; ++i)
            b |= (adj[(size_t)(i0 + i) * NN + jbase + t] != 0) << i;
        s_bits[t] = (unsigned char)b;
    }
    __syncthreads();

    const int hh = t & 7;
    const int jj = t >> 3;                   // 0..63
    float eih[IBLK];
#pragma unroll
    for (int i = 0; i < IBLK; ++i) eih[i] = eiL[(i0 + i) * NH + hh];

    float den[IBLK] = {0.f, 0.f, 0.f, 0.f};
    float acc[IBLK][DHD];
#pragma unroll
    for (int i = 0; i < IBLK; ++i)
#pragma unroll
        for (int d = 0; d < DHD; ++d) acc[i][d] = 0.f;

#pragma unroll 2
    for (int it = 0; it < JCHUNK / 64; ++it) {
        const int jl = it * 64 + jj;         // j within chunk
        const int j  = jbase + jl;
        const float ejv = ejL[j * NH + hh];
        const uint4 wd = ((const uint4*)whb)[j * NH + hh];
        const int bits = s_bits[jl];

        float e[IBLK];
#pragma unroll
        for (int i = 0; i < IBLK; ++i) {
            float s = eih[i] + ejv;          // score * log2e
            s = fmaxf(s, 0.2f * s);          // LeakyReLU
            s = (bits & (1 << i)) ? s : -192.0f;  // mask -> exp2 flushes to 0
            e[i] = __builtin_amdgcn_exp2f(s);
            den[i] += e[i];
        }
        // unpack bf16 V one dword at a time (keeps live regs low)
#pragma unroll
        for (int q = 0; q < 4; ++q) {
            const unsigned int w = (&wd.x)[q];
            const float lo = __uint_as_float(w << 16);
            const float hi = __uint_as_float(w & 0xFFFF0000u);
#pragma unroll
            for (int i = 0; i < IBLK; ++i) {
                acc[i][2 * q]     = fmaf(e[i], lo, acc[i][2 * q]);
                acc[i][2 * q + 1] = fmaf(e[i], hi, acc[i][2 * q + 1]);
            }
        }
    }

    // reduce over jj-groups within wave (lane bits 3..5)
#pragma unroll
    for (int m = 8; m <= 32; m <<= 1) {
#pragma unroll
        for (int i = 0; i < IBLK; ++i) {
            den[i] += __shfl_xor(den[i], m, 64);
#pragma unroll
            for (int d = 0; d < DHD; ++d)
                acc[i][d] += __shfl_xor(acc[i][d], m, 64);
        }
    }
    const int lane = t & 63;
    const int wv   = t >> 6;                 // 0..7
    if (lane < 8) {                          // lane == head
#pragma unroll
        for (int i = 0; i < IBLK; ++i) {
#pragma unroll
            for (int d = 0; d < DHD; ++d) s_red[wv][lane][i][d] = acc[i][d];
            s_red[wv][lane][i][8] = den[i];
        }
    }
    __syncthreads();

    {   // t bits: [8:7]=i, [6:4]=h, [3:0]=slot (0..8 active)
        const int i  = (t >> 7) & 3;
        const int hD = (t >> 4) & 7;
        const int sl = t & 15;
        if (sl < 9) {
            float v = 0.f;
#pragma unroll
            for (int w2 = 0; w2 < 8; ++w2) v += s_red[w2][hD][i][sl];
            if (sl < 8)
                pacc[(((size_t)js * NN + i0 + i) * NH + hD) * DHD + sl] = v;
            else
                pden[((size_t)js * NN + i0 + i) * NH + hD] = v;
        }
    }
}

// K3: combine j-split partials, divide, ELU, write out (H,N,Dh) flat.
__global__ __launch_bounds__(256) void gat_fin(
    const float* __restrict__ pacc, const float* __restrict__ pden,
    float* __restrict__ out)
{
    const int gid = blockIdx.x * 256 + threadIdx.x;   // < 131072
    const int d = gid & 7;
    const int hD = (gid >> 3) & 7;
    const int i = gid >> 6;
    float v = 0.f, dn = 0.f;
#pragma unroll
    for (int js = 0; js < JSPLIT; ++js) {
        v  += pacc[(((size_t)js * NN + i) * NH + hD) * DHD + d];
        dn += pden[((size_t)js * NN + i) * NH + hD];
    }
    float r = v / dn;
    r = (r > 0.f) ? r : expm1f(r);           // ELU(alpha=1)
    out[(size_t)hD * (NN * DHD) + (size_t)i * DHD + d] = r;
}

extern "C" void kernel_launch(void* const* d_in, const int* in_sizes, int n_in,
                              void* d_out, int out_size, void* d_ws, size_t ws_size,
                              hipStream_t stream) {
    const float* h   = (const float*)d_in[0];
    const int*   adj = (const int*)d_in[1];
    const float* Ww  = (const float*)d_in[2];
    const float* Wb  = (const float*)d_in[3];
    const float* aw  = (const float*)d_in[4];
    const float* ab  = (const float*)d_in[5];
    float* out = (float*)d_out;

    char* ws = (char*)d_ws;
    unsigned short* whb = (unsigned short*)ws;            // 256 KB
    float* eiL  = (float*)(ws + 262144);                  // 64 KB
    float* ejL  = (float*)(ws + 327680);                  // 64 KB
    float* pacc = (float*)(ws + 393216);                  // 4*2048*64*4 = 2 MB
    float* pden = (float*)(ws + 2490368);                 // 256 KB

    gat_pre<<<NN / 4, 256, 0, stream>>>(h, Ww, Wb, aw, ab, whb, eiL, ejL);
    gat_main<<<(NN / IBLK) * JSPLIT, 512, 0, stream>>>(adj, whb, eiL, ejL, pacc, pden);
    gat_fin<<<NN * ODIM / 256, 256, 0, stream>>>(pacc, pden, out);
}

// Round 6
// 49.287 us; speedup vs baseline: 1.1599x; 1.1599x over previous
//
#include <hip/hip_runtime.h>
#include <math.h>

#define NN 2048
#define INDIM 256
#define ODIM 64
#define NH 8
#define DHD 8
#define LOG2E 1.44269504088896340736f
#define JSPLIT 4
#define JCHUNK (NN / JSPLIT)   // 512
#define IBLK 4

// K1: wh = h@W^T + b (stored bf16 [j][h][d]); eiL=(ei+ab)*log2e; ejL=ej*log2e.
// grid 512 x 256 thr; 4 nodes/block, one wave per node (lane = out col).
__global__ __launch_bounds__(256) void gat_pre(
    const float* __restrict__ h, const float* __restrict__ Ww,
    const float* __restrict__ Wb, const float* __restrict__ aw,
    const float* __restrict__ ab,
    unsigned short* __restrict__ whb, float* __restrict__ eiL,
    float* __restrict__ ejL)
{
    __shared__ float sH[IBLK][INDIM];        // 4 KB
    const int t = threadIdx.x;
    const int n0 = blockIdx.x * 4;
    ((float4*)&sH[0][0])[t] = ((const float4*)(h + (size_t)n0 * INDIM))[t];
    __syncthreads();

    const int o  = t & 63;
    const int wv = t >> 6;                   // node within block
    const int n  = n0 + wv;
    const float4* w4 = (const float4*)(Ww + (size_t)o * INDIM);
    float acc = 0.f;
#pragma unroll 8
    for (int k = 0; k < INDIM / 4; ++k) {
        const float4 wk = w4[k];
        const float4 hv = *(const float4*)&sH[wv][k * 4];
        acc = fmaf(wk.x, hv.x, acc); acc = fmaf(wk.y, hv.y, acc);
        acc = fmaf(wk.z, hv.z, acc); acc = fmaf(wk.w, hv.w, acc);
    }
    acc += Wb[o];

    // bf16 RNE pack of wh
    {
        unsigned int u = __float_as_uint(acc);
        unsigned int r = (u + 0x7FFF + ((u >> 16) & 1)) >> 16;
        whb[(size_t)n * ODIM + o] = (unsigned short)r;
    }

    const int d = o & 7;
    float pi = acc * aw[d];
    float pj = acc * aw[NH + d];
    pi += __shfl_xor(pi, 1, 64); pj += __shfl_xor(pj, 1, 64);
    pi += __shfl_xor(pi, 2, 64); pj += __shfl_xor(pj, 2, 64);
    pi += __shfl_xor(pi, 4, 64); pj += __shfl_xor(pj, 4, 64);
    if (d == 0) {
        const int hd = o >> 3;
        eiL[n * NH + hd] = (pi + ab[0]) * LOG2E;
        ejL[n * NH + hd] = pj * LOG2E;
    }
}

// K2: block = (i-tile of 4 rows) x (j-chunk of 512). 2048 blocks x 512 thr
// (8 waves). Thread = (jj 0..63, hh 0..7). Writes partial acc/den to ws.
// NO min-waves launch_bounds arg: R3/R5 both spilled from its VGPR cap
// (1024,4 -> 64; 512,8 -> 32). Natural live set ~58 VGPR -> 8 waves/SIMD.
__global__ __launch_bounds__(512) void gat_main(
    const int* __restrict__ adj, const unsigned short* __restrict__ whb,
    const float* __restrict__ eiL, const float* __restrict__ ejL,
    float* __restrict__ pacc, float* __restrict__ pden)
{
    __shared__ unsigned char s_bits[JCHUNK]; // 512 B
    __shared__ float s_red[8][8][IBLK][9];   // 9.2 KB: wave, head, i, d/den
    const int t  = threadIdx.x;
    const int i0 = (blockIdx.x >> 2) * IBLK;
    const int js = blockIdx.x & 3;
    const int jbase = js * JCHUNK;

    {   // bit-pack 4 adjacency rows for this j-chunk
        unsigned int b = 0;
#pragma unroll
        for (int i = 0; i < IBLK; ++i)
            b |= (adj[(size_t)(i0 + i) * NN + jbase + t] != 0) << i;
        s_bits[t] = (unsigned char)b;
    }
    __syncthreads();

    const int hh = t & 7;
    const int jj = t >> 3;                   // 0..63
    float eih[IBLK];
#pragma unroll
    for (int i = 0; i < IBLK; ++i) eih[i] = eiL[(i0 + i) * NH + hh];

    float den[IBLK] = {0.f, 0.f, 0.f, 0.f};
    float acc[IBLK][DHD];
#pragma unroll
    for (int i = 0; i < IBLK; ++i)
#pragma unroll
        for (int d = 0; d < DHD; ++d) acc[i][d] = 0.f;

#pragma unroll 2
    for (int it = 0; it < JCHUNK / 64; ++it) {
        const int jl = it * 64 + jj;         // j within chunk
        const int j  = jbase + jl;
        const float ejv = ejL[j * NH + hh];
        const uint4 wd = ((const uint4*)whb)[j * NH + hh];
        const int bits = s_bits[jl];

        float e[IBLK];
#pragma unroll
        for (int i = 0; i < IBLK; ++i) {
            float s = eih[i] + ejv;          // score * log2e
            s = fmaxf(s, 0.2f * s);          // LeakyReLU
            s = (bits & (1 << i)) ? s : -192.0f;  // mask -> exp2 flushes to 0
            e[i] = __builtin_amdgcn_exp2f(s);
            den[i] += e[i];
        }
        // unpack bf16 V one dword at a time (keeps live regs low)
#pragma unroll
        for (int q = 0; q < 4; ++q) {
            const unsigned int w = (&wd.x)[q];
            const float lo = __uint_as_float(w << 16);
            const float hi = __uint_as_float(w & 0xFFFF0000u);
#pragma unroll
            for (int i = 0; i < IBLK; ++i) {
                acc[i][2 * q]     = fmaf(e[i], lo, acc[i][2 * q]);
                acc[i][2 * q + 1] = fmaf(e[i], hi, acc[i][2 * q + 1]);
            }
        }
    }

    // reduce over jj-groups within wave (lane bits 3..5)
#pragma unroll
    for (int m = 8; m <= 32; m <<= 1) {
#pragma unroll
        for (int i = 0; i < IBLK; ++i) {
            den[i] += __shfl_xor(den[i], m, 64);
#pragma unroll
            for (int d = 0; d < DHD; ++d)
                acc[i][d] += __shfl_xor(acc[i][d], m, 64);
        }
    }
    const int lane = t & 63;
    const int wv   = t >> 6;                 // 0..7
    if (lane < 8) {                          // lane == head
#pragma unroll
        for (int i = 0; i < IBLK; ++i) {
#pragma unroll
            for (int d = 0; d < DHD; ++d) s_red[wv][lane][i][d] = acc[i][d];
            s_red[wv][lane][i][8] = den[i];
        }
    }
    __syncthreads();

    {   // t bits: [8:7]=i, [6:4]=h, [3:0]=slot (0..8 active)
        const int i  = (t >> 7) & 3;
        const int hD = (t >> 4) & 7;
        const int sl = t & 15;
        if (sl < 9) {
            float v = 0.f;
#pragma unroll
            for (int w2 = 0; w2 < 8; ++w2) v += s_red[w2][hD][i][sl];
            if (sl < 8)
                pacc[(((size_t)js * NN + i0 + i) * NH + hD) * DHD + sl] = v;
            else
                pden[((size_t)js * NN + i0 + i) * NH + hD] = v;
        }
    }
}

// K3: combine j-split partials, divide, ELU, write out (H,N,Dh) flat.
__global__ __launch_bounds__(256) void gat_fin(
    const float* __restrict__ pacc, const float* __restrict__ pden,
    float* __restrict__ out)
{
    const int gid = blockIdx.x * 256 + threadIdx.x;   // < 131072
    const int d = gid & 7;
    const int hD = (gid >> 3) & 7;
    const int i = gid >> 6;
    float v = 0.f, dn = 0.f;
#pragma unroll
    for (int js = 0; js < JSPLIT; ++js) {
        v  += pacc[(((size_t)js * NN + i) * NH + hD) * DHD + d];
        dn += pden[((size_t)js * NN + i) * NH + hD];
    }
    float r = v / dn;
    r = (r > 0.f) ? r : expm1f(r);           // ELU(alpha=1)
    out[(size_t)hD * (NN * DHD) + (size_t)i * DHD + d] = r;
}

extern "C" void kernel_launch(void* const* d_in, const int* in_sizes, int n_in,
                              void* d_out, int out_size, void* d_ws, size_t ws_size,
                              hipStream_t stream) {
    const float* h   = (const float*)d_in[0];
    const int*   adj = (const int*)d_in[1];
    const float* Ww  = (const float*)d_in[2];
    const float* Wb  = (const float*)d_in[3];
    const float* aw  = (const float*)d_in[4];
    const float* ab  = (const float*)d_in[5];
    float* out = (float*)d_out;

    char* ws = (char*)d_ws;
    unsigned short* whb = (unsigned short*)ws;            // 256 KB
    float* eiL  = (float*)(ws + 262144);                  // 64 KB
    float* ejL  = (float*)(ws + 327680);                  // 64 KB
    float* pacc = (float*)(ws + 393216);                  // 4*2048*64*4 = 2 MB
    float* pden = (float*)(ws + 2490368);                 // 256 KB

    gat_pre<<<NN / 4, 256, 0, stream>>>(h, Ww, Wb, aw, ab, whb, eiL, ejL);
    gat_main<<<(NN / IBLK) * JSPLIT, 512, 0, stream>>>(adj, whb, eiL, ejL, pacc, pden);
    gat_fin<<<NN * ODIM / 256, 256, 0, stream>>>(pacc, pden, out);
}

// Round 7
// 43.141 us; speedup vs baseline: 1.3252x; 1.1425x over previous
//
#include <hip/hip_runtime.h>
#include <math.h>

#define NN 2048
#define INDIM 256
#define ODIM 64
#define NH 8
#define DHD 8
#define LOG2E 1.44269504088896340736f
#define IBLK 4

// K1: wh = h@W^T + b (stored bf16 [j][h][d]); eiL=(ei+ab)*log2e; ejL=ej*log2e.
// grid 512 x 256 thr; 4 nodes/block, one wave per node (lane = out col).
__global__ __launch_bounds__(256) void gat_pre(
    const float* __restrict__ h, const float* __restrict__ Ww,
    const float* __restrict__ Wb, const float* __restrict__ aw,
    const float* __restrict__ ab,
    unsigned short* __restrict__ whb, float* __restrict__ eiL,
    float* __restrict__ ejL)
{
    __shared__ float sH[IBLK][INDIM];        // 4 KB
    const int t = threadIdx.x;
    const int n0 = blockIdx.x * 4;
    ((float4*)&sH[0][0])[t] = ((const float4*)(h + (size_t)n0 * INDIM))[t];
    __syncthreads();

    const int o  = t & 63;
    const int wv = t >> 6;                   // node within block
    const int n  = n0 + wv;
    const float4* w4 = (const float4*)(Ww + (size_t)o * INDIM);
    float acc = 0.f;
#pragma unroll 8
    for (int k = 0; k < INDIM / 4; ++k) {
        const float4 wk = w4[k];
        const float4 hv = *(const float4*)&sH[wv][k * 4];
        acc = fmaf(wk.x, hv.x, acc); acc = fmaf(wk.y, hv.y, acc);
        acc = fmaf(wk.z, hv.z, acc); acc = fmaf(wk.w, hv.w, acc);
    }
    acc += Wb[o];

    // bf16 RNE pack of wh
    {
        unsigned int u = __float_as_uint(acc);
        unsigned int r = (u + 0x7FFF + ((u >> 16) & 1)) >> 16;
        whb[(size_t)n * ODIM + o] = (unsigned short)r;
    }

    const int d = o & 7;
    float pi = acc * aw[d];
    float pj = acc * aw[NH + d];
    pi += __shfl_xor(pi, 1, 64); pj += __shfl_xor(pj, 1, 64);
    pi += __shfl_xor(pi, 2, 64); pj += __shfl_xor(pj, 2, 64);
    pi += __shfl_xor(pi, 4, 64); pj += __shfl_xor(pj, 4, 64);
    if (d == 0) {
        const int hd = o >> 3;
        eiL[n * NH + hd] = (pi + ab[0]) * LOG2E;
        ejL[n * NH + hd] = pj * LOG2E;
    }
}

// K2: 4 i-rows per block, FULL j-range (no split). 512 blocks x 512 thr
// (8 waves). Thread = (jj 0..63, hh 0..7). Register double-buffer prefetch
// of (ej, wh) covers L2 latency inside the wave. Final divide+ELU fused.
// No min-waves launch_bounds arg (R3/R5 spill lesson); live set ~65 VGPR.
__global__ __launch_bounds__(512) void gat_main(
    const int* __restrict__ adj, const unsigned short* __restrict__ whb,
    const float* __restrict__ eiL, const float* __restrict__ ejL,
    float* __restrict__ out)
{
    __shared__ unsigned char s_bits[NN];     // 2 KB
    __shared__ float s_red[8][8][IBLK][9];   // 9.2 KB: wave, head, i, d/den
    const int t  = threadIdx.x;
    const int i0 = blockIdx.x * IBLK;

    {   // bit-pack 4 adjacency rows: thread t owns columns 4t..4t+3
        unsigned int b0 = 0, b1 = 0, b2 = 0, b3 = 0;
#pragma unroll
        for (int i = 0; i < IBLK; ++i) {
            const int4 v = *(const int4*)(adj + (size_t)(i0 + i) * NN + 4 * t);
            b0 |= (v.x != 0) << i;
            b1 |= (v.y != 0) << i;
            b2 |= (v.z != 0) << i;
            b3 |= (v.w != 0) << i;
        }
        ((uchar4*)s_bits)[t] = make_uchar4((unsigned char)b0, (unsigned char)b1,
                                           (unsigned char)b2, (unsigned char)b3);
    }
    __syncthreads();

    const int hh = t & 7;
    const int jj = t >> 3;                   // 0..63
    float eih[IBLK];
#pragma unroll
    for (int i = 0; i < IBLK; ++i) eih[i] = eiL[(i0 + i) * NH + hh];

    float den[IBLK] = {0.f, 0.f, 0.f, 0.f};
    float acc[IBLK][DHD];
#pragma unroll
    for (int i = 0; i < IBLK; ++i)
#pragma unroll
        for (int d = 0; d < DHD; ++d) acc[i][d] = 0.f;

    const float* ejp = ejL + jj * NH + hh;
    const uint4* wp  = (const uint4*)whb + jj * NH + hh;
    const unsigned char* bp = s_bits + jj;

    // prefetch first iteration
    float pe = *ejp;
    uint4 pw = *wp;

#pragma unroll 2
    for (int it = 0; it < NN / 64; ++it) {
        const float ce = pe;
        const uint4 cw = pw;
        const int bits = *bp;
        // prefetch next (last iter reads 1 stride past whb/ejL: lands in
        // unused ws slack, values never consumed)
        ejp += 64 * NH; wp += 64 * NH; bp += 64;
        pe = *ejp;
        pw = *wp;

        float e[IBLK];
#pragma unroll
        for (int i = 0; i < IBLK; ++i) {
            float s = eih[i] + ce;           // score * log2e
            s = fmaxf(s, 0.2f * s);          // LeakyReLU
            s = (bits & (1 << i)) ? s : -192.0f;  // mask -> exp2 flushes to 0
            e[i] = __builtin_amdgcn_exp2f(s);
            den[i] += e[i];
        }
#pragma unroll
        for (int q = 0; q < 4; ++q) {
            const unsigned int w = (&cw.x)[q];
            const float lo = __uint_as_float(w << 16);
            const float hi = __uint_as_float(w & 0xFFFF0000u);
#pragma unroll
            for (int i = 0; i < IBLK; ++i) {
                acc[i][2 * q]     = fmaf(e[i], lo, acc[i][2 * q]);
                acc[i][2 * q + 1] = fmaf(e[i], hi, acc[i][2 * q + 1]);
            }
        }
    }

    // reduce over jj-groups within wave (lane bits 3..5)
#pragma unroll
    for (int m = 8; m <= 32; m <<= 1) {
#pragma unroll
        for (int i = 0; i < IBLK; ++i) {
            den[i] += __shfl_xor(den[i], m, 64);
#pragma unroll
            for (int d = 0; d < DHD; ++d)
                acc[i][d] += __shfl_xor(acc[i][d], m, 64);
        }
    }
    const int lane = t & 63;
    const int wv   = t >> 6;                 // 0..7
    if (lane < 8) {                          // lane == head
#pragma unroll
        for (int i = 0; i < IBLK; ++i) {
#pragma unroll
            for (int d = 0; d < DHD; ++d) s_red[wv][lane][i][d] = acc[i][d];
            s_red[wv][lane][i][8] = den[i];
        }
    }
    __syncthreads();

    if (t < 256) {                           // 4 i x 8 heads x 8 d
        const int i  = t >> 6;
        const int hD = (t >> 3) & 7;
        const int d  = t & 7;
        float v = 0.f, dn = 0.f;
#pragma unroll
        for (int w2 = 0; w2 < 8; ++w2) {
            v  += s_red[w2][hD][i][d];
            dn += s_red[w2][hD][i][8];
        }
        float r = v / dn;
        r = (r > 0.f) ? r : expm1f(r);       // ELU(alpha=1)
        out[(size_t)hD * (NN * DHD) + (size_t)(i0 + i) * DHD + d] = r;
    }
}

extern "C" void kernel_launch(void* const* d_in, const int* in_sizes, int n_in,
                              void* d_out, int out_size, void* d_ws, size_t ws_size,
                              hipStream_t stream) {
    const float* h   = (const float*)d_in[0];
    const int*   adj = (const int*)d_in[1];
    const float* Ww  = (const float*)d_in[2];
    const float* Wb  = (const float*)d_in[3];
    const float* aw  = (const float*)d_in[4];
    const float* ab  = (const float*)d_in[5];
    float* out = (float*)d_out;

    char* ws = (char*)d_ws;
    unsigned short* whb = (unsigned short*)ws;            // 256 KB
    float* eiL  = (float*)(ws + 262144);                  // 64 KB
    float* ejL  = (float*)(ws + 327680);                  // 64 KB
    // 128 KB slack after ejL absorbs the harmless 1-stride prefetch overrun.

    gat_pre<<<NN / 4, 256, 0, stream>>>(h, Ww, Wb, aw, ab, whb, eiL, ejL);
    gat_main<<<NN / IBLK, 512, 0, stream>>>(adj, whb, eiL, ejL, out);
}

// Round 8
// 41.513 us; speedup vs baseline: 1.3771x; 1.0392x over previous
//
#include <hip/hip_runtime.h>
#include <math.h>

#define NN 2048
#define INDIM 256
#define ODIM 64
#define NH 8
#define DHD 8
#define LOG2E 1.44269504088896340736f
#define JQ 4
#define JQL (NN / JQ)     // 512
#define ITILE 16

typedef __attribute__((ext_vector_type(4))) float f32x4;
typedef __attribute__((ext_vector_type(8))) short s16x8;

// K1: wh = h@W^T + b, stored TRANSPOSED bf16 whT[o=h*8+d][n];
// eiT[h][n] = (ei+ab)*log2e ; ejT[h][n] = ej*log2e. (layouts match gat_mfma's
// coalesced B-fragment loads). 512 blocks x 256 thr, 4 nodes/block.
__global__ __launch_bounds__(256) void gat_pre(
    const float* __restrict__ h, const float* __restrict__ Ww,
    const float* __restrict__ Wb, const float* __restrict__ aw,
    const float* __restrict__ ab,
    unsigned short* __restrict__ whT, float* __restrict__ eiT,
    float* __restrict__ ejT)
{
    __shared__ float sH[4][INDIM];           // 4 KB
    const int t = threadIdx.x;
    const int n0 = blockIdx.x * 4;
    ((float4*)&sH[0][0])[t] = ((const float4*)(h + (size_t)n0 * INDIM))[t];
    __syncthreads();

    const int o  = t & 63;
    const int wv = t >> 6;                   // node within block
    const int n  = n0 + wv;
    const float4* w4 = (const float4*)(Ww + (size_t)o * INDIM);
    float acc = 0.f;
#pragma unroll 8
    for (int k = 0; k < INDIM / 4; ++k) {
        const float4 wk = w4[k];
        const float4 hv = *(const float4*)&sH[wv][k * 4];
        acc = fmaf(wk.x, hv.x, acc); acc = fmaf(wk.y, hv.y, acc);
        acc = fmaf(wk.z, hv.z, acc); acc = fmaf(wk.w, hv.w, acc);
    }
    acc += Wb[o];

    {   // bf16 RNE pack, transposed store
        unsigned int u = __float_as_uint(acc);
        unsigned int r = (u + 0x7FFF + ((u >> 16) & 1)) >> 16;
        whT[(size_t)o * NN + n] = (unsigned short)r;
    }

    const int d = o & 7;
    float pi = acc * aw[d];
    float pj = acc * aw[NH + d];
    pi += __shfl_xor(pi, 1, 64); pj += __shfl_xor(pj, 1, 64);
    pi += __shfl_xor(pi, 2, 64); pj += __shfl_xor(pj, 2, 64);
    pi += __shfl_xor(pi, 4, 64); pj += __shfl_xor(pj, 4, 64);
    if (d == 0) {
        const int hd = o >> 3;
        eiT[(size_t)hd * NN + n] = (pi + ab[0]) * LOG2E;
        ejT[(size_t)hd * NN + n] = pj * LOG2E;
    }
}

// K2: MFMA edge kernel. Block = (i-tile 16) x (j-quarter 512), 512 thr =
// 8 waves, wave hh handles head hh. Per j-step(32): lane builds P A-frag
// (row=l&15, k=(l>>4)*8+i) in bf16, loads V B-frag (col=l&15; col 8 = ones
// column -> denominator free from MFMA), one mfma_f32_16x16x32_bf16.
// Writes 16x16 D-tile (cols 0..8 meaningful) as f32 partials to pacc.
__global__ __launch_bounds__(512) void gat_mfma(
    const int* __restrict__ adj, const unsigned short* __restrict__ whT,
    const float* __restrict__ eiT, const float* __restrict__ ejT,
    float* __restrict__ pacc)
{
    __shared__ unsigned int s_mask[ITILE][17];   // pad 17: conflict-free rows
    __shared__ float s_ej[NH][JQL];              // 16 KB
    const int t  = threadIdx.x;
    const int it = blockIdx.x >> 2;
    const int jq = blockIdx.x & 3;
    const int i0 = it * ITILE;
    const int j0 = jq * JQL;

    if (t < ITILE * 16) {                    // pack adj bits: word w = 32 j's
        const int row = t >> 4, w = t & 15;
        const int* ap = adj + (size_t)(i0 + row) * NN + j0 + w * 32;
        unsigned int b = 0;
#pragma unroll
        for (int q = 0; q < 8; ++q) {
            const int4 v = ((const int4*)ap)[q];
            b |= (unsigned)(v.x != 0) << (q * 4 + 0);
            b |= (unsigned)(v.y != 0) << (q * 4 + 1);
            b |= (unsigned)(v.z != 0) << (q * 4 + 2);
            b |= (unsigned)(v.w != 0) << (q * 4 + 3);
        }
        s_mask[row][w] = b;
    }
    for (int idx = t; idx < NH * JQL; idx += 512) {   // stage ej quarter
        const int hh = idx >> 9, jl = idx & 511;
        s_ej[hh][jl] = ejT[(size_t)hh * NN + j0 + jl];
    }
    __syncthreads();

    const int l   = t & 63;
    const int hh  = t >> 6;                  // wave = head
    const int row = l & 15;                  // A m-index AND B n-index (col)
    const int g   = l >> 4;                  // k-group (k = g*8 + i)
    const float eirow = eiT[(size_t)hh * NN + i0 + row];

    const unsigned short* vbase = whT + ((size_t)(hh * DHD + row)) * NN + j0 + g * 8;
    union { unsigned int u[4]; s16x8 v; } bconst;
    {   // col 8 -> ones column (bf16 1.0 = 0x3F80); cols 9..15 -> 0
        const unsigned int cv = (row == 8) ? 0x3F803F80u : 0u;
        bconst.u[0] = cv; bconst.u[1] = cv; bconst.u[2] = cv; bconst.u[3] = cv;
    }

    f32x4 acc = {0.f, 0.f, 0.f, 0.f};

    for (int step = 0; step < JQL / 32; ++step) {    // 16 steps
        const unsigned int mbyte = (s_mask[row][step] >> (g * 8)) & 0xFFu;
        const float4 ea = *(const float4*)&s_ej[hh][step * 32 + g * 8];
        const float4 eb = *(const float4*)&s_ej[hh][step * 32 + g * 8 + 4];

        float p[8];
        p[0] = eirow + ea.x; p[1] = eirow + ea.y;
        p[2] = eirow + ea.z; p[3] = eirow + ea.w;
        p[4] = eirow + eb.x; p[5] = eirow + eb.y;
        p[6] = eirow + eb.z; p[7] = eirow + eb.w;
#pragma unroll
        for (int i = 0; i < 8; ++i) {
            float s = fmaxf(p[i], 0.2f * p[i]);          // LeakyReLU (scaled)
            s = (mbyte & (1u << i)) ? s : -192.0f;       // mask: exp2 -> 0
            p[i] = __builtin_amdgcn_exp2f(s);
        }
        union { unsigned int u[4]; s16x8 v; } af;
#pragma unroll
        for (int q = 0; q < 4; ++q)
            asm("v_cvt_pk_bf16_f32 %0, %1, %2"
                : "=v"(af.u[q]) : "v"(p[2 * q]), "v"(p[2 * q + 1]));

        s16x8 bf;
        if (row < DHD) bf = *(const s16x8*)(vbase + step * 32);
        else           bf = bconst.v;

        acc = __builtin_amdgcn_mfma_f32_16x16x32_bf16(af.v, bf, acc, 0, 0, 0);
    }

    // D: row=(l>>4)*4+r, col=l&15 (verified layout). Store f32 partial tile.
#pragma unroll
    for (int r = 0; r < 4; ++r) {
        const int orow = g * 4 + r;
        pacc[(((size_t)(jq * NH + hh)) * NN + (i0 + orow)) * 16 + row] = acc[r];
    }
}

// K3: combine j-quarter partials, divide by den (col 8), ELU, write out.
__global__ __launch_bounds__(256) void gat_fin(
    const float* __restrict__ pacc, float* __restrict__ out)
{
    const int gid = blockIdx.x * 256 + threadIdx.x;   // < 131072
    const int d  = gid & 7;
    const int i  = (gid >> 3) & (NN - 1);
    const int hh = gid >> 14;
    float v = 0.f, dn = 0.f;
#pragma unroll
    for (int jq = 0; jq < JQ; ++jq) {
        const float* p = pacc + (((size_t)(jq * NH + hh)) * NN + i) * 16;
        v  += p[d];
        dn += p[8];
    }
    float r = v / dn;
    r = (r > 0.f) ? r : expm1f(r);           // ELU(alpha=1)
    out[gid] = r;                            // gid == hh*16384 + i*8 + d
}

extern "C" void kernel_launch(void* const* d_in, const int* in_sizes, int n_in,
                              void* d_out, int out_size, void* d_ws, size_t ws_size,
                              hipStream_t stream) {
    const float* h   = (const float*)d_in[0];
    const int*   adj = (const int*)d_in[1];
    const float* Ww  = (const float*)d_in[2];
    const float* Wb  = (const float*)d_in[3];
    const float* aw  = (const float*)d_in[4];
    const float* ab  = (const float*)d_in[5];
    float* out = (float*)d_out;

    char* ws = (char*)d_ws;
    unsigned short* whT = (unsigned short*)ws;            // 256 KB  [o][n]
    float* eiT  = (float*)(ws + 262144);                  // 64 KB   [h][n]
    float* ejT  = (float*)(ws + 327680);                  // 64 KB   [h][n]
    float* pacc = (float*)(ws + 393216);                  // 4 MB [jq][h][n][16]

    gat_pre<<<NN / 4, 256, 0, stream>>>(h, Ww, Wb, aw, ab, whT, eiT, ejT);
    gat_mfma<<<(NN / ITILE) * JQ, 512, 0, stream>>>(adj, whT, eiT, ejT, pacc);
    gat_fin<<<NN * ODIM / 256, 256, 0, stream>>>(pacc, out);
}